// Round 8
// baseline (84.334 us; speedup 1.0000x reference)
//
#include <hip/hip_runtime.h>
#include <hip/hip_bf16.h>

#define N_NODES 100000
#define DEG 16
#define D 128

typedef __bf16 bf16x8 __attribute__((ext_vector_type(8)));
typedef float f32x4 __attribute__((ext_vector_type(4)));

__device__ __forceinline__ unsigned pk2(float a, float b) {
  union { __bf16 h[2]; unsigned u; } x;
  x.h[0] = (__bf16)a; x.h[1] = (__bf16)b;
  return x.u;
}

// swizzled element index into a [128][128] ushort tile (XOR bits 3..5 of k with row bits 0..2)
__device__ __forceinline__ int swz(int row, int k) {
  return (row << 7) + (k ^ ((row & 7) << 3));
}

// Kernel 0: W [k][n] f32 -> Wt bf16 transposed [n][k], swizzled (64 blocks, 1 elem/thread)
__global__ void k_convW(const float* __restrict__ W, ushort* __restrict__ Wt) {
  int pos = (blockIdx.x << 8) + threadIdx.x;   // 0..16383
  int k = pos >> 7, n = pos & 127;
  union { __bf16 h; ushort u; } c;
  c.h = (__bf16)W[pos];
  Wt[swz(n, k)] = c.u;
}

// Kernel 1: Xp = bf16(X @ W), rows stored in permuted col order: pos p=llo*8+n <-> col n*16+llo.
// NO LDS, NO barrier: Wt (32 KB) is L1-resident per CU; each wave reads B-fragments directly
// from global. 128-row tile per block, 4 waves x 32 rows (m=0,1). Waves fully independent.
__global__ __launch_bounds__(256) void k_gemm(const float* __restrict__ X,
                                              const ushort* __restrict__ Wt,
                                              ushort* __restrict__ Xp) {
  const int tid = threadIdx.x;
  const int row0 = blockIdx.x << 7;
  const int wave = tid >> 6;
  const int lane = tid & 63;
  const int lhi = lane >> 4;           // 0..3
  const int llo = lane & 15;

  // issue all 16 A-fragment loads: lane owns row (per m), k-slice lhi*8 (per t)
  float4 t0[2][4], t1[2][4];
#pragma unroll
  for (int m = 0; m < 2; ++m) {
    int row = row0 + (wave << 5) + (m << 4) + llo;
    const float* rp = X + row * D + (lhi << 3);
    bool ok = row < N_NODES;
#pragma unroll
    for (int t = 0; t < 4; ++t) {
      t0[m][t] = ok ? *(const float4*)(rp + (t << 5)) : make_float4(0.f, 0.f, 0.f, 0.f);
      t1[m][t] = ok ? *(const float4*)(rp + (t << 5) + 4) : make_float4(0.f, 0.f, 0.f, 0.f);
    }
  }

  // convert A to bf16 (waits on A loads; B loads below are L1/L2 hits)
  bf16x8 af[2][4];
#pragma unroll
  for (int m = 0; m < 2; ++m)
#pragma unroll
    for (int t = 0; t < 4; ++t) {
      bf16x8 v;
      v[0] = (__bf16)t0[m][t].x; v[1] = (__bf16)t0[m][t].y;
      v[2] = (__bf16)t0[m][t].z; v[3] = (__bf16)t0[m][t].w;
      v[4] = (__bf16)t1[m][t].x; v[5] = (__bf16)t1[m][t].y;
      v[6] = (__bf16)t1[m][t].z; v[7] = (__bf16)t1[m][t].w;
      af[m][t] = v;
    }

  f32x4 acc[2][8];
#pragma unroll
  for (int m = 0; m < 2; ++m)
#pragma unroll
    for (int n = 0; n < 8; ++n)
      acc[m][n] = (f32x4){0.f, 0.f, 0.f, 0.f};

#pragma unroll
  for (int t = 0; t < 4; ++t) {
    const int k0 = (t << 5) + (lhi << 3);
    bf16x8 b[8];
#pragma unroll
    for (int n = 0; n < 8; ++n)
      b[n] = *(const bf16x8*)(Wt + swz((n << 4) + llo, k0));
#pragma unroll
    for (int m = 0; m < 2; ++m)
#pragma unroll
      for (int n = 0; n < 8; ++n)
        acc[m][n] = __builtin_amdgcn_mfma_f32_16x16x32_bf16(af[m][t], b[n], acc[m][n], 0, 0, 0);
  }

  // epilogue: C/D layout col=llo, row=lhi*4+r. Pack 8 cols (n=0..7) -> uint4 per (m,r).
#pragma unroll
  for (int m = 0; m < 2; ++m) {
#pragma unroll
    for (int r = 0; r < 4; ++r) {
      int row = row0 + (wave << 5) + (m << 4) + (lhi << 2) + r;
      if (row < N_NODES) {
        uint4 v;
        v.x = pk2(acc[m][0][r], acc[m][1][r]);
        v.y = pk2(acc[m][2][r], acc[m][3][r]);
        v.z = pk2(acc[m][4][r], acc[m][5][r]);
        v.w = pk2(acc[m][6][r], acc[m][7][r]);
        *(uint4*)(Xp + row * D + (llo << 3)) = v;
      }
    }
  }
}

// Kernel 2: out[i] = sum_{e} Xp[ci[e]]  (one wave per row; Xp rows are col-permuted)
// Quarter-wave scheme: group g = lane>>4 handles edges 4g..4g+3; lane j = lane&15
// loads 16 B (positions j*8..j*8+8 = logical cols {n*16+j}). Cross-group reduce
// via shfl_xor(16,32); group-g store covers contiguous cols 32g..32g+31.
__global__ __launch_bounds__(256) void k_spmm(const ushort* __restrict__ Xp,
                                              const int* __restrict__ ci,
                                              float* __restrict__ out) {
  const int wave = threadIdx.x >> 6;
  const int lane = threadIdx.x & 63;
  const int row = (blockIdx.x << 2) + wave;
  if (row >= N_NODES) return;
  const int g = lane >> 4;
  const int j = lane & 15;

  int idx = 0;
  if (lane < DEG) idx = __builtin_nontemporal_load(ci + row * DEG + lane);

  uint4 v[4];
#pragma unroll
  for (int e = 0; e < 4; ++e) {
    int col = __shfl(idx, (g << 2) + e);
    v[e] = *(const uint4*)(Xp + col * D + (j << 3));
  }

  float acc[8];
#pragma unroll
  for (int n = 0; n < 8; ++n) acc[n] = 0.f;
#pragma unroll
  for (int e = 0; e < 4; ++e) {
    acc[0] += __uint_as_float(v[e].x << 16);
    acc[1] += __uint_as_float(v[e].x & 0xffff0000u);
    acc[2] += __uint_as_float(v[e].y << 16);
    acc[3] += __uint_as_float(v[e].y & 0xffff0000u);
    acc[4] += __uint_as_float(v[e].z << 16);
    acc[5] += __uint_as_float(v[e].z & 0xffff0000u);
    acc[6] += __uint_as_float(v[e].w << 16);
    acc[7] += __uint_as_float(v[e].w & 0xffff0000u);
  }

#pragma unroll
  for (int n = 0; n < 8; ++n) {
    acc[n] += __shfl_xor(acc[n], 16);
    acc[n] += __shfl_xor(acc[n], 32);
  }

  // lane (g,j): acc[n] holds col n*16+j; store acc[2g]->col 32g+j, acc[2g+1]->col 32g+16+j
  float* op = out + row * D + (g << 5) + j;
  __builtin_nontemporal_store(acc[(g << 1)], op);
  __builtin_nontemporal_store(acc[(g << 1) + 1], op + 16);
}

extern "C" void kernel_launch(void* const* d_in, const int* in_sizes, int n_in,
                              void* d_out, int out_size, void* d_ws, size_t ws_size,
                              hipStream_t stream) {
  const float* X = (const float*)d_in[0];
  const float* W = (const float*)d_in[1];
  const int* ci = (const int*)d_in[3];

  ushort* Wt = (ushort*)d_ws;                 // 32 KB
  ushort* Xp = (ushort*)d_ws + 128 * 128;     // 25.6 MB bf16 X' (permuted rows)
  float* out = (float*)d_out;

  k_convW<<<64, 256, 0, stream>>>(W, Wt);
  k_gemm<<<(N_NODES + 127) / 128, 256, 0, stream>>>(X, Wt, Xp);
  k_spmm<<<N_NODES / 4, 256, 0, stream>>>(Xp, ci, out);
}